// Round 6
// baseline (318.158 us; speedup 1.0000x reference)
//
#include <hip/hip_runtime.h>
#include <math.h>

typedef unsigned int u32;
typedef unsigned long long u64;
typedef float nfloat4 __attribute__((ext_vector_type(4)));

#define AL(p) __hip_atomic_load((p), __ATOMIC_RELAXED, __HIP_MEMORY_SCOPE_AGENT)

// ---------------------------------------------------------------------------
// Exact 0.99-quantile of |x| via 2-level radix select on float bit patterns.
//  K1 hist_top : 2048-bin hist of bits[30:20] (8-replica LDS) -> g1;
//                last block (ticket) scans g1 -> B1, residual rank k1.
//  K2 hist_low : elements with topbits==B1: global-atomic hist of low 20 bits
//                into 1M bins (h2, in ws).
//  K3 chunk_fin: 1024 blocks reduce h2 into 1024 chunk sums (atomicAdd);
//                last block (ticket) scans chunk sums + winning chunk's 1024
//                bins -> exact bits of sorted[k] -> scale.
//  K4 quantize : out = clip(rint(x/scale),-128,127)*scale (bit-exact STE).
// Cross-block comm is ONLY via device-scope atomics + one ACQ_REL ticket per
// block after __syncthreads (which drains vmcnt). NO __threadfence anywhere
// (R4: per-thread fence = ~175us of buffer_wbl2 serialization).
// ws layout (u32): [0..2047] g1 | [2048..2055] sc | [2056..2059] tickets
//   [2060..3083] chunk sums | [4096..4096+1M) h2
// sc: 0=B1 1=k1 4=scale bits
// ---------------------------------------------------------------------------

#define G1 0
#define SC 2048
#define TK 2056
#define CS 2060
#define H2 4096
#define ZERO_U32 (4096 + (1 << 20))

__global__ __launch_bounds__(1024) void hist_top(const u32* __restrict__ x,
                                                 u32* __restrict__ ws,
                                                 long long n, u32 k) {
  u32* g1 = ws + G1;
  u32* sc = ws + SC;
  __shared__ u32 h[2048 * 8];  // 8 interleaved replicas, 64 KB
  const int t = threadIdx.x;
  for (int i = t; i < 2048 * 8; i += 1024) h[i] = 0;
  __syncthreads();

  const u32 r = (u32)(t & 7);
  const long long n4 = n >> 2;
  const long long stride = (long long)gridDim.x * 1024;
  const uint4* x4 = (const uint4*)x;
  for (long long i = (long long)blockIdx.x * 1024 + t; i < n4; i += stride) {
    uint4 v = x4[i];
    atomicAdd(&h[(((v.x & 0x7fffffffu) >> 20) << 3) + r], 1u);
    atomicAdd(&h[(((v.y & 0x7fffffffu) >> 20) << 3) + r], 1u);
    atomicAdd(&h[(((v.z & 0x7fffffffu) >> 20) << 3) + r], 1u);
    atomicAdd(&h[(((v.w & 0x7fffffffu) >> 20) << 3) + r], 1u);
  }
  for (long long i = (n4 << 2) + (long long)blockIdx.x * 1024 + t; i < n;
       i += stride)
    atomicAdd(&h[(((x[i] & 0x7fffffffu) >> 20) << 3) + r], 1u);
  __syncthreads();
  for (int i = t; i < 2048; i += 1024) {
    u32 c = 0;
#pragma unroll
    for (int j = 0; j < 8; ++j) c += h[(i << 3) + j];
    if (c) atomicAdd(&g1[i], c);
  }
  __syncthreads();  // compiler drains vmcnt before s_barrier -> adds visible
  __shared__ u32 isLast;
  if (t == 0) {
    u32 done = __hip_atomic_fetch_add(ws + TK, 1u, __ATOMIC_ACQ_REL,
                                      __HIP_MEMORY_SCOPE_AGENT);
    isLast = (done == (u32)(gridDim.x - 1));
  }
  __syncthreads();
  if (!isLast) return;
  // ---- fused scan of g1 (only the final block runs this) ----
  u32* s = h;  // reuse LDS
  const u32 c0 = AL(&g1[2 * t]);
  const u32 c1 = AL(&g1[2 * t + 1]);
  const u32 sum = c0 + c1;
  s[t] = sum;
  __syncthreads();
  for (int off = 1; off < 1024; off <<= 1) {
    u32 add = (t >= off) ? s[t - off] : 0u;
    __syncthreads();
    s[t] += add;
    __syncthreads();
  }
  u32 ex = s[t] - sum;
  if (k >= ex && k < ex + c0) { sc[0] = 2 * t; sc[1] = k - ex; }
  ex += c0;
  if (k >= ex && k < ex + c1) { sc[0] = 2 * t + 1; sc[1] = k - ex; }
}

__global__ __launch_bounds__(1024) void hist_low(const u32* __restrict__ x,
                                                 u32* __restrict__ ws,
                                                 long long n) {
  const u32 B1 = ws[SC + 0];
  u32* h2 = ws + H2;
  const int t = threadIdx.x;
  const long long n4 = n >> 2;
  const long long stride = (long long)gridDim.x * 1024;
  const uint4* x4 = (const uint4*)x;
  for (long long i = (long long)blockIdx.x * 1024 + t; i < n4; i += stride) {
    uint4 v = x4[i];
    u32 a;
    a = v.x & 0x7fffffffu; if ((a >> 20) == B1) atomicAdd(&h2[a & 0xFFFFFu], 1u);
    a = v.y & 0x7fffffffu; if ((a >> 20) == B1) atomicAdd(&h2[a & 0xFFFFFu], 1u);
    a = v.z & 0x7fffffffu; if ((a >> 20) == B1) atomicAdd(&h2[a & 0xFFFFFu], 1u);
    a = v.w & 0x7fffffffu; if ((a >> 20) == B1) atomicAdd(&h2[a & 0xFFFFFu], 1u);
  }
  for (long long i = (n4 << 2) + (long long)blockIdx.x * 1024 + t; i < n;
       i += stride) {
    u32 a = x[i] & 0x7fffffffu;
    if ((a >> 20) == B1) atomicAdd(&h2[a & 0xFFFFFu], 1u);
  }
}

__global__ __launch_bounds__(256) void chunk_fin(u32* __restrict__ ws,
                                                 const float* __restrict__ gamma) {
  const u32* h2 = ws + H2;
  u32* cs = ws + CS;
  u32* sc = ws + SC;
  const int t = threadIdx.x;
  const int b = blockIdx.x;
  // reduce 1024 bins of chunk b
  uint4 v = ((const uint4*)(h2 + (size_t)b * 1024))[t];
  u32 sum = v.x + v.y + v.z + v.w;
#pragma unroll
  for (int off = 32; off > 0; off >>= 1) sum += __shfl_down(sum, off, 64);
  __shared__ u32 w[4];
  if ((t & 63) == 0) w[t >> 6] = sum;
  __syncthreads();
  __shared__ u32 isLast;
  if (t == 0) {
    const u32 total = w[0] + w[1] + w[2] + w[3];
    if (total) atomicAdd(&cs[b], total);
    u32 done = __hip_atomic_fetch_add(ws + TK + 1, 1u, __ATOMIC_ACQ_REL,
                                      __HIP_MEMORY_SCOPE_AGENT);
    isLast = (done == (u32)(gridDim.x - 1));
  }
  __syncthreads();
  if (!isLast) return;
  // ---- final block: scan chunk sums, then winning chunk's bins ----
  __shared__ u32 s[256];
  __shared__ u32 sChunk, sK2;
  const u32 k1 = sc[1];
  u32 c[4];
#pragma unroll
  for (int j = 0; j < 4; ++j) c[j] = AL(&cs[4 * t + j]);
  u32 mySum = c[0] + c[1] + c[2] + c[3];
  s[t] = mySum;
  __syncthreads();
  for (int off = 1; off < 256; off <<= 1) {
    u32 add = (t >= off) ? s[t - off] : 0u;
    __syncthreads();
    s[t] += add;
    __syncthreads();
  }
  u32 ex = s[t] - mySum;
#pragma unroll
  for (int j = 0; j < 4; ++j) {
    if (k1 >= ex && k1 < ex + c[j]) {
      sChunk = (u32)(4 * t + j);
      sK2 = k1 - ex;
    }
    ex += c[j];
  }
  __syncthreads();
  const u32 csel = sChunk;
  const u32 k2 = sK2;
  // scan the 1024 bins of chunk csel (read-only data from prior kernel)
  u32 c2[4];
#pragma unroll
  for (int j = 0; j < 4; ++j) c2[j] = h2[(size_t)csel * 1024 + 4 * t + j];
  mySum = c2[0] + c2[1] + c2[2] + c2[3];
  __syncthreads();
  s[t] = mySum;
  __syncthreads();
  for (int off = 1; off < 256; off <<= 1) {
    u32 add = (t >= off) ? s[t - off] : 0u;
    __syncthreads();
    s[t] += add;
    __syncthreads();
  }
  ex = s[t] - mySum;
#pragma unroll
  for (int j = 0; j < 4; ++j) {
    if (k2 >= ex && k2 < ex + c2[j]) {
      const u32 bits = (sc[0] << 20) | (csel * 1024u + (u32)(4 * t + j));
      const float q = __uint_as_float(bits);
      float gm = gamma[0];
      gm = fminf(fmaxf(gm, 0.1f), 10.0f);
      sc[4] = __float_as_uint((q / 127.0f) * gm);
    }
    ex += c2[j];
  }
}

__global__ __launch_bounds__(256) void quantize(const float* __restrict__ x,
                                                float* __restrict__ out,
                                                const u32* __restrict__ ws,
                                                long long n) {
  const float scale = __uint_as_float(ws[SC + 4]);
  const long long n4 = n >> 2;
  const long long stride = (long long)gridDim.x * 256;
  const float4* x4 = (const float4*)x;
  nfloat4* o4 = (nfloat4*)out;
  for (long long i = (long long)blockIdx.x * 256 + threadIdx.x; i < n4;
       i += stride) {
    float4 v = x4[i];
    nfloat4 o;
    o.x = fminf(fmaxf(rintf(v.x / scale), -128.0f), 127.0f) * scale;
    o.y = fminf(fmaxf(rintf(v.y / scale), -128.0f), 127.0f) * scale;
    o.z = fminf(fmaxf(rintf(v.z / scale), -128.0f), 127.0f) * scale;
    o.w = fminf(fmaxf(rintf(v.w / scale), -128.0f), 127.0f) * scale;
    __builtin_nontemporal_store(o, &o4[i]);
  }
  for (long long i = (n4 << 2) + (long long)blockIdx.x * 256 + threadIdx.x;
       i < n; i += stride) {
    float v = x[i];
    out[i] = fminf(fmaxf(rintf(v / scale), -128.0f), 127.0f) * scale;
  }
}

extern "C" void kernel_launch(void* const* d_in, const int* in_sizes, int n_in,
                              void* d_out, int out_size, void* d_ws,
                              size_t ws_size, hipStream_t stream) {
  const u32* xbits = (const u32*)d_in[0];
  const float* gamma = (const float*)d_in[1];
  const long long n = (long long)in_sizes[0];
  u32* ws = (u32*)d_ws;

  const u32 k = (u32)llround(0.99 * (double)n);

  (void)hipMemsetAsync(ws, 0, (size_t)ZERO_U32 * sizeof(u32), stream);
  hist_top<<<512, 1024, 0, stream>>>(xbits, ws, n, k);
  hist_low<<<512, 1024, 0, stream>>>(xbits, ws, n);
  chunk_fin<<<1024, 256, 0, stream>>>(ws, gamma);
  quantize<<<2048, 256, 0, stream>>>((const float*)d_in[0], (float*)d_out, ws,
                                     n);
}

// Round 7
// 282.040 us; speedup vs baseline: 1.1281x; 1.1281x over previous
//
#include <hip/hip_runtime.h>
#include <math.h>

typedef unsigned int u32;
typedef float nfloat4 __attribute__((ext_vector_type(4)));

// ---------------------------------------------------------------------------
// Exact 0.99-quantile of |x| via 2-level radix select on float bit patterns.
// R3 structure (287.5us champion), dispatches 8 -> 5 via REDUNDANT SCANS:
// rank-selection scans are pure functions of small L2-hot histograms, so
// consumer blocks recompute them in a cheap prologue instead of reading a
// published scalar. NO cross-block atomics/tickets/fences (R4: per-thread
// fence = +175us; R6: per-block ACQ_REL tickets = +31us). All producer->
// consumer visibility via kernel boundaries only.
//  K1 hist_top    : 2048-bin hist of bits[30:20], 8-replica LDS -> g1
//  K2 hist_low    : prologue re-scans g1 -> B1; elements with top==B1:
//                   global-atomic hist of low 20 bits -> h2 (1M bins)
//  K3 chunk_reduce: 1024 blocks sum h2 chunks -> cs[1024] (plain stores)
//  K4 quantize    : prologue re-scans g1 -> (B1,k1), cs -> (chunk,k2),
//                   h2[chunk] -> exact bits -> scale (kept in registers);
//                   then out = clip(rint(x/scale),-128,127)*scale
// ws layout (u32): [0..2047] g1 | [2048..3071] cs | [4096..4096+1M) h2
// ---------------------------------------------------------------------------

#define G1 0
#define CS 2048
#define H2 4096
#define ZERO_U32 (4096 + (1 << 20))

__global__ __launch_bounds__(1024) void hist_top(const u32* __restrict__ x,
                                                 u32* __restrict__ ws,
                                                 long long n) {
  u32* g1 = ws + G1;
  __shared__ u32 h[2048 * 8];  // 8 interleaved replicas, 64 KB
  const int t = threadIdx.x;
  for (int i = t; i < 2048 * 8; i += 1024) h[i] = 0;
  __syncthreads();

  const u32 r = (u32)(t & 7);
  const long long n4 = n >> 2;
  const long long stride = (long long)gridDim.x * 1024;
  const uint4* x4 = (const uint4*)x;
  for (long long i = (long long)blockIdx.x * 1024 + t; i < n4; i += stride) {
    uint4 v = x4[i];
    atomicAdd(&h[(((v.x & 0x7fffffffu) >> 20) << 3) + r], 1u);
    atomicAdd(&h[(((v.y & 0x7fffffffu) >> 20) << 3) + r], 1u);
    atomicAdd(&h[(((v.z & 0x7fffffffu) >> 20) << 3) + r], 1u);
    atomicAdd(&h[(((v.w & 0x7fffffffu) >> 20) << 3) + r], 1u);
  }
  for (long long i = (n4 << 2) + (long long)blockIdx.x * 1024 + t; i < n;
       i += stride)
    atomicAdd(&h[(((x[i] & 0x7fffffffu) >> 20) << 3) + r], 1u);
  __syncthreads();
  for (int i = t; i < 2048; i += 1024) {
    u32 c = 0;
#pragma unroll
    for (int j = 0; j < 8; ++j) c += h[(i << 3) + j];
    if (c) atomicAdd(&g1[i], c);
  }
}

__global__ __launch_bounds__(1024) void hist_low(const u32* __restrict__ x,
                                                 u32* __restrict__ ws,
                                                 long long n, u32 k) {
  // --- prologue: every block redundantly scans g1 (8 KB, L2-hot) -> B1 ---
  __shared__ u32 s[1024];
  __shared__ u32 resB1;
  const u32* g1 = ws + G1;
  u32* h2 = ws + H2;
  const int t = threadIdx.x;
  {
    const uint2 c2 = ((const uint2*)g1)[t];
    const u32 sum = c2.x + c2.y;
    s[t] = sum;
    __syncthreads();
    for (int off = 1; off < 1024; off <<= 1) {
      u32 add = (t >= off) ? s[t - off] : 0u;
      __syncthreads();
      s[t] += add;
      __syncthreads();
    }
    u32 ex = s[t] - sum;
    if (k >= ex && k < ex + c2.x) resB1 = 2 * t;
    ex += c2.x;
    if (k >= ex && k < ex + c2.y) resB1 = 2 * t + 1;
    __syncthreads();
  }
  const u32 B1 = resB1;

  // --- hot loop: identical to R3 ---
  const long long n4 = n >> 2;
  const long long stride = (long long)gridDim.x * 1024;
  const uint4* x4 = (const uint4*)x;
  for (long long i = (long long)blockIdx.x * 1024 + t; i < n4; i += stride) {
    uint4 v = x4[i];
    u32 a;
    a = v.x & 0x7fffffffu; if ((a >> 20) == B1) atomicAdd(&h2[a & 0xFFFFFu], 1u);
    a = v.y & 0x7fffffffu; if ((a >> 20) == B1) atomicAdd(&h2[a & 0xFFFFFu], 1u);
    a = v.z & 0x7fffffffu; if ((a >> 20) == B1) atomicAdd(&h2[a & 0xFFFFFu], 1u);
    a = v.w & 0x7fffffffu; if ((a >> 20) == B1) atomicAdd(&h2[a & 0xFFFFFu], 1u);
  }
  for (long long i = (n4 << 2) + (long long)blockIdx.x * 1024 + t; i < n;
       i += stride) {
    u32 a = x[i] & 0x7fffffffu;
    if ((a >> 20) == B1) atomicAdd(&h2[a & 0xFFFFFu], 1u);
  }
}

// 1024 blocks: block b sums h2[b*1024 .. b*1024+1024) -> cs[b] (plain store)
__global__ __launch_bounds__(256) void chunk_reduce(u32* __restrict__ ws) {
  const u32* h2 = ws + H2;
  u32* cs = ws + CS;
  const int t = threadIdx.x;
  uint4 v = ((const uint4*)(h2 + (size_t)blockIdx.x * 1024))[t];
  u32 sum = v.x + v.y + v.z + v.w;
#pragma unroll
  for (int off = 32; off > 0; off >>= 1) sum += __shfl_down(sum, off, 64);
  __shared__ u32 w[4];
  if ((t & 63) == 0) w[t >> 6] = sum;
  __syncthreads();
  if (t == 0) cs[blockIdx.x] = w[0] + w[1] + w[2] + w[3];
}

__global__ __launch_bounds__(256) void quantize(const float* __restrict__ x,
                                                float* __restrict__ out,
                                                const u32* __restrict__ ws,
                                                const float* __restrict__ gamma,
                                                long long n, u32 k) {
  // --- prologue: every block redundantly derives scale from L2-hot hists ---
  __shared__ u32 s[256];
  __shared__ u32 r0, r1;
  __shared__ float fscale;
  const u32* g1 = ws + G1;
  const u32* cs = ws + CS;
  const u32* h2 = ws + H2;
  const int t = threadIdx.x;

  // scan A: g1 (2048 bins, 8/thread) -> B1, k1
  u32 B1, k1;
  {
    u32 c[8], sum = 0;
#pragma unroll
    for (int j = 0; j < 8; ++j) { c[j] = g1[t * 8 + j]; sum += c[j]; }
    s[t] = sum;
    __syncthreads();
    for (int off = 1; off < 256; off <<= 1) {
      u32 add = (t >= off) ? s[t - off] : 0u;
      __syncthreads();
      s[t] += add;
      __syncthreads();
    }
    u32 ex = s[t] - sum;
#pragma unroll
    for (int j = 0; j < 8; ++j) {
      if (k >= ex && k < ex + c[j]) { r0 = (u32)(t * 8 + j); r1 = k - ex; }
      ex += c[j];
    }
    __syncthreads();
    B1 = r0; k1 = r1;
  }
  // scan B: cs (1024 chunk sums, 4/thread) -> chunk, k2
  u32 chunk, k2;
  {
    u32 c[4], sum = 0;
#pragma unroll
    for (int j = 0; j < 4; ++j) { c[j] = cs[t * 4 + j]; sum += c[j]; }
    __syncthreads();  // protect r0/r1 reads above before rewrite below
    s[t] = sum;
    __syncthreads();
    for (int off = 1; off < 256; off <<= 1) {
      u32 add = (t >= off) ? s[t - off] : 0u;
      __syncthreads();
      s[t] += add;
      __syncthreads();
    }
    u32 ex = s[t] - sum;
#pragma unroll
    for (int j = 0; j < 4; ++j) {
      if (k1 >= ex && k1 < ex + c[j]) { r0 = (u32)(t * 4 + j); r1 = k1 - ex; }
      ex += c[j];
    }
    __syncthreads();
    chunk = r0; k2 = r1;
  }
  // scan C: h2[chunk*1024 ..] (1024 bins, 4/thread) -> exact bits -> scale
  {
    u32 c[4], sum = 0;
#pragma unroll
    for (int j = 0; j < 4; ++j) {
      c[j] = h2[(size_t)chunk * 1024 + t * 4 + j];
      sum += c[j];
    }
    __syncthreads();
    s[t] = sum;
    __syncthreads();
    for (int off = 1; off < 256; off <<= 1) {
      u32 add = (t >= off) ? s[t - off] : 0u;
      __syncthreads();
      s[t] += add;
      __syncthreads();
    }
    u32 ex = s[t] - sum;
#pragma unroll
    for (int j = 0; j < 4; ++j) {
      if (k2 >= ex && k2 < ex + c[j]) {
        const u32 bits = (B1 << 20) | (chunk * 1024u + (u32)(t * 4 + j));
        const float q = __uint_as_float(bits);
        float gm = gamma[0];
        gm = fminf(fmaxf(gm, 0.1f), 10.0f);
        fscale = (q / 127.0f) * gm;
      }
      ex += c[j];
    }
    __syncthreads();
  }
  const float scale = fscale;

  // --- hot loop: identical to R3 ---
  const long long n4 = n >> 2;
  const long long stride = (long long)gridDim.x * 256;
  const float4* x4 = (const float4*)x;
  nfloat4* o4 = (nfloat4*)out;
  for (long long i = (long long)blockIdx.x * 256 + t; i < n4; i += stride) {
    float4 v = x4[i];
    nfloat4 o;
    o.x = fminf(fmaxf(rintf(v.x / scale), -128.0f), 127.0f) * scale;
    o.y = fminf(fmaxf(rintf(v.y / scale), -128.0f), 127.0f) * scale;
    o.z = fminf(fmaxf(rintf(v.z / scale), -128.0f), 127.0f) * scale;
    o.w = fminf(fmaxf(rintf(v.w / scale), -128.0f), 127.0f) * scale;
    __builtin_nontemporal_store(o, &o4[i]);
  }
  for (long long i = (n4 << 2) + (long long)blockIdx.x * 256 + t; i < n;
       i += stride) {
    float v = x[i];
    out[i] = fminf(fmaxf(rintf(v / scale), -128.0f), 127.0f) * scale;
  }
}

extern "C" void kernel_launch(void* const* d_in, const int* in_sizes, int n_in,
                              void* d_out, int out_size, void* d_ws,
                              size_t ws_size, hipStream_t stream) {
  const u32* xbits = (const u32*)d_in[0];
  const float* gamma = (const float*)d_in[1];
  const long long n = (long long)in_sizes[0];
  u32* ws = (u32*)d_ws;

  const u32 k = (u32)llround(0.99 * (double)n);

  (void)hipMemsetAsync(ws, 0, (size_t)ZERO_U32 * sizeof(u32), stream);
  hist_top<<<512, 1024, 0, stream>>>(xbits, ws, n);
  hist_low<<<512, 1024, 0, stream>>>(xbits, ws, n, k);
  chunk_reduce<<<1024, 256, 0, stream>>>(ws);
  quantize<<<2048, 256, 0, stream>>>((const float*)d_in[0], (float*)d_out, ws,
                                     gamma, n, k);
}